// Round 4
// baseline (256.663 us; speedup 1.0000x reference)
//
#include <hip/hip_runtime.h>
#include <math.h>

#define B_ 8192
#define D_ 4096
#define K_ 64
#define EPSF 1e-8f
#define LN2F 0.69314718056f

#define ENT_GRID 2048
#define ENT_BLOCK 256

typedef float f32x4 __attribute__((ext_vector_type(4)));

// ---------------- reduction helpers ----------------

__device__ __forceinline__ float wave_reduce_f(float v) {
#pragma unroll
  for (int o = 32; o > 0; o >>= 1) v += __shfl_down(v, o);
  return v;
}

// ---------------- kernels ----------------

// zero counts[64] + sd1[64] + sd8[64] (contiguous 192 ints/floats)
__global__ void k_init(int* __restrict__ z) {
  if (threadIdx.x < 192) z[threadIdx.x] = 0;
}

// one wave per row; K_ == 64 == wavefront size: one coalesced read + ballot
__global__ void k_labels(const float* __restrict__ probs, int* __restrict__ labels,
                         int* __restrict__ counts, int* __restrict__ rowlist) {
  int row = blockIdx.x * 4 + (threadIdx.x >> 6);
  int lane = threadIdx.x & 63;
  float p = probs[(size_t)row * K_ + lane];
  unsigned long long m = __ballot(p > 0.5f);
  if (lane == 0) {
    int k = __ffsll(m) - 1;
    if (k >= 0) {
      labels[row] = k;
      int pos = atomicAdd(&counts[k], 1);
      rowlist[k * B_ + pos] = row;
    }
  }
}

// block per row: w = 1/max(norm,eps); class-sum of diag via 64-slot atomics
__global__ __launch_bounds__(256) void k_norms(const float* __restrict__ acts,
                                               const int* __restrict__ labels,
                                               float* __restrict__ wout,
                                               float* __restrict__ sd) {
  __shared__ float lds[4];
  int row = blockIdx.x;
  const float4* rp = (const float4*)(acts + (size_t)row * D_);
  int t = threadIdx.x;
  float4 v0 = rp[t];
  float4 v1 = rp[t + 256];
  float4 v2 = rp[t + 512];
  float4 v3 = rp[t + 768];
  float s = v0.x * v0.x + v0.y * v0.y + v0.z * v0.z + v0.w * v0.w;
  s += v1.x * v1.x + v1.y * v1.y + v1.z * v1.z + v1.w * v1.w;
  s += v2.x * v2.x + v2.y * v2.y + v2.z * v2.z + v2.w * v2.w;
  s += v3.x * v3.x + v3.y * v3.y + v3.z * v3.z + v3.w * v3.w;
  s = wave_reduce_f(s);
  int wid = t >> 6;
  if ((t & 63) == 0) lds[wid] = s;
  __syncthreads();
  if (t == 0) {
    s = lds[0] + lds[1] + lds[2] + lds[3];
    float n = sqrtf(s);
    float w = 1.0f / fmaxf(n, EPSF);
    wout[row] = w;
    atomicAdd(&sd[labels[row]], s * w * w);  // diag contribution, class-bucketed
  }
}

// block = (class k, column chunk cc of 1024, row split); register accumulation only.
// NT loads: last use of acts, keep L3 clean for the other tensor.
__global__ __launch_bounds__(256) void k_classsum(const float* __restrict__ acts,
                                                  const int* __restrict__ counts,
                                                  const int* __restrict__ rowlist,
                                                  const float* __restrict__ warr,
                                                  float* __restrict__ Cpart, int nsplit) {
  int bid = blockIdx.x;
  int k = bid & 63;
  int cc = (bid >> 6) & 3;
  int split = bid >> 8;  // 0..nsplit-1
  int cnt = counts[k];
  int beg = (cnt * split) / nsplit;
  int end = (cnt * (split + 1)) / nsplit;
  int t = threadIdx.x;
  int col = cc * 1024 + 4 * t;
  const int* rl = rowlist + k * B_;
  f32x4 acc0 = 0.f, acc1 = 0.f, acc2 = 0.f, acc3 = 0.f;
  int r = beg;
  for (; r + 4 <= end; r += 4) {
    int row0 = rl[r], row1 = rl[r + 1], row2 = rl[r + 2], row3 = rl[r + 3];
    float w0 = warr[row0], w1 = warr[row1], w2 = warr[row2], w3 = warr[row3];
    f32x4 v0 = __builtin_nontemporal_load((const f32x4*)(acts + (size_t)row0 * D_ + col));
    f32x4 v1 = __builtin_nontemporal_load((const f32x4*)(acts + (size_t)row1 * D_ + col));
    f32x4 v2 = __builtin_nontemporal_load((const f32x4*)(acts + (size_t)row2 * D_ + col));
    f32x4 v3 = __builtin_nontemporal_load((const f32x4*)(acts + (size_t)row3 * D_ + col));
    acc0 += w0 * v0;
    acc1 += w1 * v1;
    acc2 += w2 * v2;
    acc3 += w3 * v3;
  }
  for (; r < end; ++r) {
    int row0 = rl[r];
    float w0 = warr[row0];
    f32x4 v0 = __builtin_nontemporal_load((const f32x4*)(acts + (size_t)row0 * D_ + col));
    acc0 += w0 * v0;
  }
  acc0 += acc1 + acc2 + acc3;
  *(f32x4*)(Cpart + ((size_t)split * K_ + k) * D_ + col) = acc0;
}

// grid 256: block (k = b>>2, quarter q = b&3) -> partial ||C_k||^2 over 1024 cols
__global__ void k_msm(const float* __restrict__ Cpart, int nsplit, float* __restrict__ msp) {
  __shared__ float lds[4];
  int k = blockIdx.x >> 2;
  int q = blockIdx.x & 3;
  int t = threadIdx.x;
  int col = q * 1024 + 4 * t;
  f32x4 c = 0.f;
  for (int s = 0; s < nsplit; ++s)
    c += *(const f32x4*)(Cpart + ((size_t)s * K_ + k) * D_ + col);
  float sq = c.x * c.x + c.y * c.y + c.z * c.z + c.w * c.w;
  sq = wave_reduce_f(sq);
  int wid = t >> 6;
  if ((t & 63) == 0) lds[wid] = sq;
  __syncthreads();
  if (t == 0) msp[blockIdx.x] = lds[0] + lds[1] + lds[2] + lds[3];
}

__device__ __forceinline__ float ent1(float p) {
  p = fminf(fmaxf(p, EPSF), 1.0f - EPSF);
  float q = 1.0f - p;
  float lp = __builtin_amdgcn_logf(p);  // v_log_f32: log2
  float lq = __builtin_amdgcn_logf(fmaxf(q, 1e-38f));
  return -(p * lp + q * lq);
}

__device__ __forceinline__ float ent4(f32x4 v) {
  return ent1(v.x) + ent1(v.y) + ent1(v.z) + ent1(v.w);
}

// fused binary entropy over both masks; ILP-8 nontemporal loads; per-block partials in double
__global__ __launch_bounds__(ENT_BLOCK) void k_entropy(const f32x4* __restrict__ m1,
                                                       const f32x4* __restrict__ m8,
                                                       double* __restrict__ entpart) {
  __shared__ float lds[8];
  const int NTH = ENT_GRID * ENT_BLOCK;  // 524288 threads; 16 f32x4 each per mask
  int tid = blockIdx.x * ENT_BLOCK + threadIdx.x;
  float s1 = 0.f, s8 = 0.f;
#pragma unroll
  for (int o = 0; o < 4; ++o) {
    f32x4 a[4], b[4];
#pragma unroll
    for (int j = 0; j < 4; ++j) {
      int idx = tid + (o * 4 + j) * NTH;
      a[j] = __builtin_nontemporal_load(&m1[idx]);
      b[j] = __builtin_nontemporal_load(&m8[idx]);
    }
#pragma unroll
    for (int j = 0; j < 4; ++j) {
      s1 += ent4(a[j]);
      s8 += ent4(b[j]);
    }
  }
  s1 = wave_reduce_f(s1);
  s8 = wave_reduce_f(s8);
  int wid = threadIdx.x >> 6;
  if ((threadIdx.x & 63) == 0) { lds[wid] = s1; lds[4 + wid] = s8; }
  __syncthreads();
  if (threadIdx.x == 0) {
    float t1 = lds[0] + lds[1] + lds[2] + lds[3];
    float t8 = lds[4] + lds[5] + lds[6] + lds[7];
    entpart[blockIdx.x]            = (double)(t1 * LN2F);
    entpart[ENT_GRID + blockIdx.x] = (double)(t8 * LN2F);
  }
}

__global__ void k_final(const double* __restrict__ entpart, const int* __restrict__ counts,
                        const float* __restrict__ sd1, const float* __restrict__ sd8,
                        const float* __restrict__ msp1, const float* __restrict__ msp8,
                        float* __restrict__ out) {
  __shared__ double dl[8];
  int t = threadIdx.x;
  double e1 = 0.0, e8 = 0.0;
  for (int i = t; i < ENT_GRID; i += 256) {
    e1 += entpart[i];
    e8 += entpart[ENT_GRID + i];
  }
#pragma unroll
  for (int o = 32; o > 0; o >>= 1) {
    e1 += __shfl_down(e1, o);
    e8 += __shfl_down(e8, o);
  }
  int wid = t >> 6;
  if ((t & 63) == 0) { dl[wid] = e1; dl[4 + wid] = e8; }
  __syncthreads();
  float pcm1 = 0.f, pcm8 = 0.f, valid = 0.f;
  if (t < K_) {
    float mSm1 = msp1[t * 4] + msp1[t * 4 + 1] + msp1[t * 4 + 2] + msp1[t * 4 + 3];
    float mSm8 = msp8[t * 4] + msp8[t * 4 + 1] + msp8[t * 4 + 2] + msp8[t * 4 + 3];
    float n = (float)counts[t];
    bool v = (n >= 2.0f);
    float np = fmaxf(0.5f * n * (n - 1.0f), 1.0f);
    valid = v ? 1.0f : 0.f;
    pcm1 = v ? 0.5f * (mSm1 - sd1[t]) / np : 0.f;
    pcm8 = v ? 0.5f * (mSm8 - sd8[t]) / np : 0.f;
  }
#pragma unroll
  for (int o = 32; o > 0; o >>= 1) {
    pcm1 += __shfl_down(pcm1, o);
    pcm8 += __shfl_down(pcm8, o);
    valid += __shfl_down(valid, o);
  }
  if (t == 0) {
    double etot1 = dl[0] + dl[1] + dl[2] + dl[3];
    double etot8 = dl[4] + dl[5] + dl[6] + dl[7];
    float sp1 = (float)(etot1 / (double)((long long)B_ * D_));
    float sp8 = (float)(etot8 / (double)((long long)B_ * D_));
    float cs1 = (valid > 0.f) ? pcm1 / fmaxf(valid, 1.0f) : 0.f;
    float cs8 = (valid > 0.f) ? pcm8 / fmaxf(valid, 1.0f) : 0.f;
    float sim1 = -cs1, sim8 = -cs8;
    out[0] = sim1 + sim8 + 0.001f * (sp1 + sp8);
    out[1] = sim1;
    out[2] = sim8;
    out[3] = sp1;
    out[4] = sp8;
  }
}

// ---------------- launcher ----------------
// ws layout (bytes):
//   0        : double entpart[2][2048]     32768
//   32768    : int    labels[B]            32768
//   65536    : int    counts[64]           256   \
//   65792    : float  sd1[64]              256    } zeroed together (192 words)
//   66048    : float  sd8[64]              256   /
//   66304    : float  msp1[256]            1024
//   67328    : float  msp8[256]            1024
//   69632    : float  warr1[B]             32768
//   102400   : float  warr8[B]             32768
//   135168   : int    rowlist[K][B]        2097152
//   2232320  : float  Cpart[nsplit][K][D]  nsplit MB

extern "C" void kernel_launch(void* const* d_in, const int* in_sizes, int n_in,
                              void* d_out, int out_size, void* d_ws, size_t ws_size,
                              hipStream_t stream) {
  const float* probs = (const float*)d_in[0];
  const float* a1 = (const float*)d_in[1];
  const float* a8 = (const float*)d_in[2];
  const float* m1 = (const float*)d_in[3];
  const float* m8 = (const float*)d_in[4];
  float* out = (float*)d_out;
  char* ws = (char*)d_ws;

  double* entpart = (double*)(ws + 0);
  int* labels = (int*)(ws + 32768);
  int* counts = (int*)(ws + 65536);
  float* sd1 = (float*)(ws + 65792);
  float* sd8 = (float*)(ws + 66048);
  float* msp1 = (float*)(ws + 66304);
  float* msp8 = (float*)(ws + 67328);
  float* warr1 = (float*)(ws + 69632);
  float* warr8 = (float*)(ws + 102400);
  int* rowlist = (int*)(ws + 135168);
  float* Cpart = (float*)(ws + 2232320);

  // adaptive row-split count for classsum partials (1 MB per split)
  int nsplit = (ws_size >= (size_t)2232320 + 8u * 1024 * 1024 + 65536) ? 8 : 4;

  k_init<<<1, 256, 0, stream>>>(counts);
  k_labels<<<B_ / 4, 256, 0, stream>>>(probs, labels, counts, rowlist);
  // acts_1b: norm pass fills L3, classsum re-reads L3-hot (NT on last use)
  k_norms<<<B_, 256, 0, stream>>>(a1, labels, warr1, sd1);
  k_classsum<<<256 * nsplit, 256, 0, stream>>>(a1, counts, rowlist, warr1, Cpart, nsplit);
  k_msm<<<256, 256, 0, stream>>>(Cpart, nsplit, msp1);
  // acts_8b
  k_norms<<<B_, 256, 0, stream>>>(a8, labels, warr8, sd8);
  k_classsum<<<256 * nsplit, 256, 0, stream>>>(a8, counts, rowlist, warr8, Cpart, nsplit);
  k_msm<<<256, 256, 0, stream>>>(Cpart, nsplit, msp8);
  // masks last: NT stream, order-independent, doesn't disturb acts L3 residency
  k_entropy<<<ENT_GRID, 256, 0, stream>>>((const f32x4*)m1, (const f32x4*)m8, entpart);
  k_final<<<1, 256, 0, stream>>>(entpart, counts, sd1, sd8, msp1, msp8, out);
}

// Round 5
// 239.340 us; speedup vs baseline: 1.0724x; 1.0724x over previous
//
#include <hip/hip_runtime.h>
#include <math.h>

#define B_ 8192
#define D_ 4096
#define K_ 64
#define EPSF 1e-8f
#define LN2F 0.69314718056f
#define ENT_GRID 2048
#define NSPLIT 8

typedef float f32x4 __attribute__((ext_vector_type(4)));

// ---------------- helpers ----------------

__device__ __forceinline__ float wave_reduce_f(float v) {
#pragma unroll
  for (int o = 32; o > 0; o >>= 1) v += __shfl_down(v, o);
  return v;
}

__device__ __forceinline__ float ent1(float p) {
  p = fminf(fmaxf(p, EPSF), 1.0f - EPSF);
  float q = 1.0f - p;
  float lp = __builtin_amdgcn_logf(p);  // v_log_f32: log2
  float lq = __builtin_amdgcn_logf(fmaxf(q, 1e-38f));
  return -(p * lp + q * lq);
}

__device__ __forceinline__ float ent4(f32x4 v) {
  return ent1(v.x) + ent1(v.y) + ent1(v.z) + ent1(v.w);
}

// ---------------- block bodies ----------------

// one row: w = 1/max(||a||,eps); class-bucketed diag sum via 64-slot atomics
__device__ __forceinline__ void norms_body(const float* __restrict__ acts,
                                           const int* __restrict__ labels,
                                           float* __restrict__ wout, float* __restrict__ sd,
                                           int row, float* lds) {
  const float4* rp = (const float4*)(acts + (size_t)row * D_);
  int t = threadIdx.x;
  float4 v0 = rp[t];
  float4 v1 = rp[t + 256];
  float4 v2 = rp[t + 512];
  float4 v3 = rp[t + 768];
  float s = v0.x * v0.x + v0.y * v0.y + v0.z * v0.z + v0.w * v0.w;
  s += v1.x * v1.x + v1.y * v1.y + v1.z * v1.z + v1.w * v1.w;
  s += v2.x * v2.x + v2.y * v2.y + v2.z * v2.z + v2.w * v2.w;
  s += v3.x * v3.x + v3.y * v3.y + v3.z * v3.z + v3.w * v3.w;
  s = wave_reduce_f(s);
  if ((t & 63) == 0) lds[t >> 6] = s;
  __syncthreads();
  if (t == 0) {
    s = lds[0] + lds[1] + lds[2] + lds[3];
    float w = 1.0f / fmaxf(sqrtf(s), EPSF);
    wout[row] = w;
    atomicAdd(&sd[labels[row]], s * w * w);
  }
}

// one entropy chunk (1/2048 of one mask), ILP-16 NT loads
__device__ __forceinline__ void entropy_body(const f32x4* __restrict__ m,
                                             double* __restrict__ entp, int blk, float* lds) {
  const int NTH = ENT_GRID * 256;
  int tid = blk * 256 + threadIdx.x;
  float s = 0.f;
#pragma unroll
  for (int o = 0; o < 4; ++o) {
    f32x4 a[4];
#pragma unroll
    for (int j = 0; j < 4; ++j) a[j] = __builtin_nontemporal_load(&m[tid + (o * 4 + j) * NTH]);
#pragma unroll
    for (int j = 0; j < 4; ++j) s += ent4(a[j]);
  }
  s = wave_reduce_f(s);
  if ((threadIdx.x & 63) == 0) lds[4 + (threadIdx.x >> 6)] = s;
  __syncthreads();
  if (threadIdx.x == 0) entp[blk] = (double)((lds[4] + lds[5] + lds[6] + lds[7]) * LN2F);
}

// class partial sum: bid2 = (split<<8)|(cc<<6)|k ; REGULAR loads (want L3 hits)
__device__ __forceinline__ void classsum_body(const float* __restrict__ acts,
                                              const int* __restrict__ counts,
                                              const int* __restrict__ rowlist,
                                              const float* __restrict__ warr,
                                              float* __restrict__ Cpart, int bid2) {
  int k = bid2 & 63;
  int cc = (bid2 >> 6) & 3;
  int split = bid2 >> 8;  // 0..NSPLIT-1
  int cnt = counts[k];
  int beg = (cnt * split) / NSPLIT;
  int end = (cnt * (split + 1)) / NSPLIT;
  int col = cc * 1024 + 4 * threadIdx.x;
  const int* rl = rowlist + k * B_;
  f32x4 acc0 = 0.f, acc1 = 0.f, acc2 = 0.f, acc3 = 0.f;
  int r = beg;
  for (; r + 4 <= end; r += 4) {
    int row0 = rl[r], row1 = rl[r + 1], row2 = rl[r + 2], row3 = rl[r + 3];
    float w0 = warr[row0], w1 = warr[row1], w2 = warr[row2], w3 = warr[row3];
    f32x4 v0 = *(const f32x4*)(acts + (size_t)row0 * D_ + col);
    f32x4 v1 = *(const f32x4*)(acts + (size_t)row1 * D_ + col);
    f32x4 v2 = *(const f32x4*)(acts + (size_t)row2 * D_ + col);
    f32x4 v3 = *(const f32x4*)(acts + (size_t)row3 * D_ + col);
    acc0 += w0 * v0;
    acc1 += w1 * v1;
    acc2 += w2 * v2;
    acc3 += w3 * v3;
  }
  for (; r < end; ++r) {
    int row0 = rl[r];
    float w0 = warr[row0];
    f32x4 v0 = *(const f32x4*)(acts + (size_t)row0 * D_ + col);
    acc0 += w0 * v0;
  }
  acc0 += acc1 + acc2 + acc3;
  *(f32x4*)(Cpart + ((size_t)split * K_ + k) * D_ + col) = acc0;
}

// b in [0,256): k=b>>2, quarter q=b&3 -> partial ||C_k||^2 over 1024 cols
__device__ __forceinline__ void msm_body(const float* __restrict__ Cpart,
                                         float* __restrict__ msp, int b, float* lds) {
  int k = b >> 2;
  int q = b & 3;
  int col = q * 1024 + 4 * threadIdx.x;
  f32x4 c = 0.f;
#pragma unroll
  for (int s = 0; s < NSPLIT; ++s)
    c += *(const f32x4*)(Cpart + ((size_t)s * K_ + k) * D_ + col);
  float sq = c.x * c.x + c.y * c.y + c.z * c.z + c.w * c.w;
  sq = wave_reduce_f(sq);
  if ((threadIdx.x & 63) == 0) lds[threadIdx.x >> 6] = sq;
  __syncthreads();
  if (threadIdx.x == 0) msp[b] = lds[0] + lds[1] + lds[2] + lds[3];
}

// ---------------- kernels ----------------

__global__ void k_init(int* __restrict__ z) {
  if (threadIdx.x < 192) z[threadIdx.x] = 0;
}

__global__ void k_labels(const float* __restrict__ probs, int* __restrict__ labels,
                         int* __restrict__ counts, int* __restrict__ rowlist) {
  int row = blockIdx.x * 4 + (threadIdx.x >> 6);
  int lane = threadIdx.x & 63;
  float p = probs[(size_t)row * K_ + lane];
  unsigned long long m = __ballot(p > 0.5f);
  if (lane == 0) {
    int k = __ffsll(m) - 1;
    if (k >= 0) {
      labels[row] = k;
      int pos = atomicAdd(&counts[k], 1);
      rowlist[k * B_ + pos] = row;
    }
  }
}

// norms(a1) [8192 blocks] + entropy(m1) [2048 blocks], interleaved 4:1
__global__ __launch_bounds__(256) void k_fused1(const float* __restrict__ a1,
                                                const f32x4* __restrict__ m1,
                                                const int* __restrict__ labels,
                                                float* __restrict__ warr1,
                                                float* __restrict__ sd1,
                                                double* __restrict__ entpart) {
  __shared__ float lds[8];
  int g = blockIdx.x / 5;
  int r = blockIdx.x % 5;
  if (r < 4)
    norms_body(a1, labels, warr1, sd1, g * 4 + r, lds);
  else
    entropy_body(m1, entpart, g, lds);
}

// classsum(a1, L3-hot) [2048 blocks] + entropy(m8) [2048 blocks], interleaved 1:1
__global__ __launch_bounds__(256) void k_fused2(const float* __restrict__ a1,
                                                const f32x4* __restrict__ m8,
                                                const int* __restrict__ counts,
                                                const int* __restrict__ rowlist,
                                                const float* __restrict__ warr1,
                                                float* __restrict__ Cpart,
                                                double* __restrict__ entpart8) {
  __shared__ float lds[8];
  if (blockIdx.x & 1)
    entropy_body(m8, entpart8, blockIdx.x >> 1, lds);
  else
    classsum_body(a1, counts, rowlist, warr1, Cpart, blockIdx.x >> 1);
}

// msm1 [256 blocks] + norms(a8) [8192 blocks]
__global__ __launch_bounds__(256) void k_fused3(const float* __restrict__ a8,
                                                const int* __restrict__ labels,
                                                float* __restrict__ warr8,
                                                float* __restrict__ sd8,
                                                const float* __restrict__ Cpart,
                                                float* __restrict__ msp1) {
  __shared__ float lds[8];
  if (blockIdx.x < 256)
    msm_body(Cpart, msp1, blockIdx.x, lds);
  else
    norms_body(a8, labels, warr8, sd8, blockIdx.x - 256, lds);
}

__global__ __launch_bounds__(256) void k_fused4(const float* __restrict__ a8,
                                                const int* __restrict__ counts,
                                                const int* __restrict__ rowlist,
                                                const float* __restrict__ warr8,
                                                float* __restrict__ Cpart) {
  classsum_body(a8, counts, rowlist, warr8, Cpart, blockIdx.x);
}

__global__ void k_msm8(const float* __restrict__ Cpart, float* __restrict__ msp8) {
  __shared__ float lds[8];
  msm_body(Cpart, msp8, blockIdx.x, lds);
}

__global__ void k_final(const double* __restrict__ entpart, const int* __restrict__ counts,
                        const float* __restrict__ sd1, const float* __restrict__ sd8,
                        const float* __restrict__ msp1, const float* __restrict__ msp8,
                        float* __restrict__ out) {
  __shared__ double dl[8];
  int t = threadIdx.x;
  double e1 = 0.0, e8 = 0.0;
  for (int i = t; i < ENT_GRID; i += 256) {
    e1 += entpart[i];
    e8 += entpart[ENT_GRID + i];
  }
#pragma unroll
  for (int o = 32; o > 0; o >>= 1) {
    e1 += __shfl_down(e1, o);
    e8 += __shfl_down(e8, o);
  }
  int wid = t >> 6;
  if ((t & 63) == 0) { dl[wid] = e1; dl[4 + wid] = e8; }
  __syncthreads();
  float pcm1 = 0.f, pcm8 = 0.f, valid = 0.f;
  if (t < K_) {
    float mSm1 = msp1[t * 4] + msp1[t * 4 + 1] + msp1[t * 4 + 2] + msp1[t * 4 + 3];
    float mSm8 = msp8[t * 4] + msp8[t * 4 + 1] + msp8[t * 4 + 2] + msp8[t * 4 + 3];
    float n = (float)counts[t];
    bool v = (n >= 2.0f);
    float np = fmaxf(0.5f * n * (n - 1.0f), 1.0f);
    valid = v ? 1.0f : 0.f;
    pcm1 = v ? 0.5f * (mSm1 - sd1[t]) / np : 0.f;
    pcm8 = v ? 0.5f * (mSm8 - sd8[t]) / np : 0.f;
  }
#pragma unroll
  for (int o = 32; o > 0; o >>= 1) {
    pcm1 += __shfl_down(pcm1, o);
    pcm8 += __shfl_down(pcm8, o);
    valid += __shfl_down(valid, o);
  }
  if (t == 0) {
    double etot1 = dl[0] + dl[1] + dl[2] + dl[3];
    double etot8 = dl[4] + dl[5] + dl[6] + dl[7];
    float sp1 = (float)(etot1 / (double)((long long)B_ * D_));
    float sp8 = (float)(etot8 / (double)((long long)B_ * D_));
    float cs1 = (valid > 0.f) ? pcm1 / fmaxf(valid, 1.0f) : 0.f;
    float cs8 = (valid > 0.f) ? pcm8 / fmaxf(valid, 1.0f) : 0.f;
    float sim1 = -cs1, sim8 = -cs8;
    out[0] = sim1 + sim8 + 0.001f * (sp1 + sp8);
    out[1] = sim1;
    out[2] = sim8;
    out[3] = sp1;
    out[4] = sp8;
  }
}

// ---------------- launcher ----------------
// ws layout (bytes):
//   0        : double entpart[2][2048]     32768
//   32768    : int    labels[B]            32768
//   65536    : int    counts[64]           256   \
//   65792    : float  sd1[64]              256    } zeroed together (192 words)
//   66048    : float  sd8[64]              256   /
//   66304    : float  msp1[256]            1024
//   67328    : float  msp8[256]            1024
//   69632    : float  warr1[B]             32768
//   102400   : float  warr8[B]             32768
//   135168   : int    rowlist[K][B]        2097152
//   2232320  : float  Cpart[NSPLIT][K][D]  8388608
//   total ~10.6 MB (ws_size observed ~539 MB)

extern "C" void kernel_launch(void* const* d_in, const int* in_sizes, int n_in,
                              void* d_out, int out_size, void* d_ws, size_t ws_size,
                              hipStream_t stream) {
  const float* probs = (const float*)d_in[0];
  const float* a1 = (const float*)d_in[1];
  const float* a8 = (const float*)d_in[2];
  const float* m1 = (const float*)d_in[3];
  const float* m8 = (const float*)d_in[4];
  float* out = (float*)d_out;
  char* ws = (char*)d_ws;

  double* entpart = (double*)(ws + 0);
  int* labels = (int*)(ws + 32768);
  int* counts = (int*)(ws + 65536);
  float* sd1 = (float*)(ws + 65792);
  float* sd8 = (float*)(ws + 66048);
  float* msp1 = (float*)(ws + 66304);
  float* msp8 = (float*)(ws + 67328);
  float* warr1 = (float*)(ws + 69632);
  float* warr8 = (float*)(ws + 102400);
  int* rowlist = (int*)(ws + 135168);
  float* Cpart = (float*)(ws + 2232320);

  k_init<<<1, 256, 0, stream>>>(counts);
  k_labels<<<B_ / 4, 256, 0, stream>>>(probs, labels, counts, rowlist);
  // norms(a1) fills L3 with a1 while m1 entropy NT-streams alongside
  k_fused1<<<10240, 256, 0, stream>>>(a1, (const f32x4*)m1, labels, warr1, sd1, entpart);
  // classsum(a1) reads L3-hot a1 while m8 entropy NT-streams alongside
  k_fused2<<<4096, 256, 0, stream>>>(a1, (const f32x4*)m8, counts, rowlist, warr1, Cpart,
                                     entpart + ENT_GRID);
  // msm1 (reads Cpart) + norms(a8) refills L3 with a8
  k_fused3<<<8448, 256, 0, stream>>>(a8, labels, warr8, sd8, Cpart, msp1);
  // classsum(a8) reads L3-hot a8
  k_fused4<<<2048, 256, 0, stream>>>(a8, counts, rowlist, warr8, Cpart);
  k_msm8<<<256, 256, 0, stream>>>(Cpart, msp8);
  k_final<<<1, 256, 0, stream>>>(entpart, counts, sd1, sd8, msp1, msp8, out);
}

// Round 6
// 183.640 us; speedup vs baseline: 1.3976x; 1.3033x over previous
//
#include <hip/hip_runtime.h>
#include <math.h>

#define B_ 8192
#define D_ 4096
#define K_ 64
#define EPSF 1e-8f
#define LN2F 0.69314718056f
#define ENT_GRID 2048
#define SPLITS 16  // wave-level splits per class (4 blocks x 4 waves)

typedef float f32x4 __attribute__((ext_vector_type(4)));

// ---------------- kernels ----------------

// zero counts[64] + sd1[64] + sd8[64] (contiguous 192 words)
__global__ void k_init(int* __restrict__ z) {
  if (threadIdx.x < 192) z[threadIdx.x] = 0;
}

// one wave per row; K_ == 64 == wavefront: one coalesced read + ballot
__global__ void k_labels(const float* __restrict__ probs, int* __restrict__ labels,
                         int* __restrict__ counts, int* __restrict__ rowlist) {
  int row = blockIdx.x * 4 + (threadIdx.x >> 6);
  int lane = threadIdx.x & 63;
  float p = probs[(size_t)row * K_ + lane];
  unsigned long long m = __ballot(p > 0.5f);
  if (lane == 0) {
    int k = __ffsll(m) - 1;
    if (k >= 0) {
      labels[row] = k;
      int pos = atomicAdd(&counts[k], 1);
      rowlist[k * B_ + pos] = row;
    }
  }
}

// Single-pass norm + weighted class sum. One WAVE per row (no __syncthreads):
// read full row (16 f32x4/lane), shfl_xor-reduce ||a||^2, w = 1/max(||a||,eps),
// acc += w*row in registers; per-wave partial written to its Cpart split.
// Grid: blocks 0..255 -> tensor a1, 256..511 -> tensor a8 (homogeneous bodies).
__global__ __launch_bounds__(256) void k_classnorm(
    const float* __restrict__ a1, const float* __restrict__ a8,
    const int* __restrict__ counts, const int* __restrict__ rowlist,
    const int* __restrict__ labels, float* __restrict__ Cpart1, float* __restrict__ Cpart8,
    float* __restrict__ sd1, float* __restrict__ sd8) {
  int bid = blockIdx.x;
  const float* a = (bid < 256) ? a1 : a8;
  float* Cpart = (bid < 256) ? Cpart1 : Cpart8;
  float* sd = (bid < 256) ? sd1 : sd8;
  bid &= 255;
  int k = bid & 63;
  int blkSplit = bid >> 6;         // 0..3
  int wave = threadIdx.x >> 6;     // 0..3
  int lane = threadIdx.x & 63;
  int split = blkSplit * 4 + wave; // 0..15
  int cnt = counts[k];
  int beg = (cnt * split) / SPLITS;
  int end = (cnt * (split + 1)) / SPLITS;
  const int* rl = rowlist + k * B_;

  f32x4 acc[16];
#pragma unroll
  for (int j = 0; j < 16; ++j) acc[j] = 0.f;

  for (int r = beg; r < end; ++r) {
    int row = rl[r];
    const f32x4* rp = (const f32x4*)(a + (size_t)row * D_);
    f32x4 v[16];
#pragma unroll
    for (int j = 0; j < 16; ++j) v[j] = rp[lane + 64 * j];  // wave reads 16KB contiguous
    float s = 0.f;
#pragma unroll
    for (int j = 0; j < 16; ++j)
      s += v[j].x * v[j].x + v[j].y * v[j].y + v[j].z * v[j].z + v[j].w * v[j].w;
#pragma unroll
    for (int o = 32; o > 0; o >>= 1) s += __shfl_xor(s, o);  // all lanes get ||a||^2
    float w = 1.0f / fmaxf(sqrtf(s), EPSF);
#pragma unroll
    for (int j = 0; j < 16; ++j) acc[j] += w * v[j];
    if (lane == 0) atomicAdd(&sd[labels[row]], s * w * w);
  }

  float* cp = Cpart + ((size_t)split * K_ + k) * D_;
#pragma unroll
  for (int j = 0; j < 16; ++j) *(f32x4*)(cp + 4 * (lane + 64 * j)) = acc[j];
}

// mSm partials: 512 blocks; b<256 -> tensor1, else tensor8. k=b>>2, quarter q=b&3.
__global__ __launch_bounds__(256) void k_msm(const float* __restrict__ Cpart1,
                                             const float* __restrict__ Cpart8,
                                             float* __restrict__ msp1,
                                             float* __restrict__ msp8) {
  __shared__ float lds[4];
  int b = blockIdx.x;
  const float* Cpart = (b < 256) ? Cpart1 : Cpart8;
  float* msp = (b < 256) ? msp1 : msp8;
  b &= 255;
  int k = b >> 2;
  int q = b & 3;
  int t = threadIdx.x;
  int col = q * 1024 + 4 * t;
  f32x4 c = 0.f;
#pragma unroll
  for (int s = 0; s < SPLITS; ++s)
    c += *(const f32x4*)(Cpart + ((size_t)s * K_ + k) * D_ + col);
  float sq = c.x * c.x + c.y * c.y + c.z * c.z + c.w * c.w;
#pragma unroll
  for (int o = 32; o > 0; o >>= 1) sq += __shfl_down(sq, o);
  if ((t & 63) == 0) lds[t >> 6] = sq;
  __syncthreads();
  if (t == 0) msp[blockIdx.x & 255] = lds[0] + lds[1] + lds[2] + lds[3];
}

__device__ __forceinline__ float ent1(float p) {
  p = fminf(fmaxf(p, EPSF), 1.0f - EPSF);
  float q = 1.0f - p;
  float lp = __builtin_amdgcn_logf(p);  // v_log_f32: log2
  float lq = __builtin_amdgcn_logf(fmaxf(q, 1e-38f));
  return -(p * lp + q * lq);
}

__device__ __forceinline__ float ent4(f32x4 v) {
  return ent1(v.x) + ent1(v.y) + ent1(v.z) + ent1(v.w);
}

// binary entropy over both masks; PLAIN loads (no NT), ILP-8, block-contiguous 64KB chunks
__global__ __launch_bounds__(256) void k_entropy(const f32x4* __restrict__ m1,
                                                 const f32x4* __restrict__ m8,
                                                 double* __restrict__ entpart) {
  __shared__ float lds[8];
  const int CHUNK = (B_ * D_ / 4) / ENT_GRID;  // 4096 f32x4 per block per mask
  int base = blockIdx.x * CHUNK;
  int t = threadIdx.x;
  float s1 = 0.f, s8 = 0.f;
#pragma unroll
  for (int o = 0; o < 4; ++o) {
    f32x4 a[4], b[4];
#pragma unroll
    for (int j = 0; j < 4; ++j) {
      int idx = base + t + (o * 4 + j) * 256;
      a[j] = m1[idx];
      b[j] = m8[idx];
    }
#pragma unroll
    for (int j = 0; j < 4; ++j) {
      s1 += ent4(a[j]);
      s8 += ent4(b[j]);
    }
  }
#pragma unroll
  for (int o = 32; o > 0; o >>= 1) {
    s1 += __shfl_down(s1, o);
    s8 += __shfl_down(s8, o);
  }
  int wid = t >> 6;
  if ((t & 63) == 0) { lds[wid] = s1; lds[4 + wid] = s8; }
  __syncthreads();
  if (t == 0) {
    float t1 = lds[0] + lds[1] + lds[2] + lds[3];
    float t8 = lds[4] + lds[5] + lds[6] + lds[7];
    entpart[blockIdx.x]            = (double)(t1 * LN2F);
    entpart[ENT_GRID + blockIdx.x] = (double)(t8 * LN2F);
  }
}

__global__ void k_final(const double* __restrict__ entpart, const int* __restrict__ counts,
                        const float* __restrict__ sd1, const float* __restrict__ sd8,
                        const float* __restrict__ msp1, const float* __restrict__ msp8,
                        float* __restrict__ out) {
  __shared__ double dl[8];
  int t = threadIdx.x;
  double e1 = 0.0, e8 = 0.0;
  for (int i = t; i < ENT_GRID; i += 256) {
    e1 += entpart[i];
    e8 += entpart[ENT_GRID + i];
  }
#pragma unroll
  for (int o = 32; o > 0; o >>= 1) {
    e1 += __shfl_down(e1, o);
    e8 += __shfl_down(e8, o);
  }
  int wid = t >> 6;
  if ((t & 63) == 0) { dl[wid] = e1; dl[4 + wid] = e8; }
  __syncthreads();
  float pcm1 = 0.f, pcm8 = 0.f, valid = 0.f;
  if (t < K_) {
    float mSm1 = msp1[t * 4] + msp1[t * 4 + 1] + msp1[t * 4 + 2] + msp1[t * 4 + 3];
    float mSm8 = msp8[t * 4] + msp8[t * 4 + 1] + msp8[t * 4 + 2] + msp8[t * 4 + 3];
    float n = (float)counts[t];
    bool v = (n >= 2.0f);
    float np = fmaxf(0.5f * n * (n - 1.0f), 1.0f);
    valid = v ? 1.0f : 0.f;
    pcm1 = v ? 0.5f * (mSm1 - sd1[t]) / np : 0.f;
    pcm8 = v ? 0.5f * (mSm8 - sd8[t]) / np : 0.f;
  }
#pragma unroll
  for (int o = 32; o > 0; o >>= 1) {
    pcm1 += __shfl_down(pcm1, o);
    pcm8 += __shfl_down(pcm8, o);
    valid += __shfl_down(valid, o);
  }
  if (t == 0) {
    double etot1 = dl[0] + dl[1] + dl[2] + dl[3];
    double etot8 = dl[4] + dl[5] + dl[6] + dl[7];
    float sp1 = (float)(etot1 / (double)((long long)B_ * D_));
    float sp8 = (float)(etot8 / (double)((long long)B_ * D_));
    float cs1 = (valid > 0.f) ? pcm1 / fmaxf(valid, 1.0f) : 0.f;
    float cs8 = (valid > 0.f) ? pcm8 / fmaxf(valid, 1.0f) : 0.f;
    float sim1 = -cs1, sim8 = -cs8;
    out[0] = sim1 + sim8 + 0.001f * (sp1 + sp8);
    out[1] = sim1;
    out[2] = sim8;
    out[3] = sp1;
    out[4] = sp8;
  }
}

// ---------------- launcher ----------------
// ws layout (bytes):
//   0        : double entpart[2][2048]      32768
//   32768    : int    labels[B]             32768
//   65536    : int    counts[64]            256  \
//   65792    : float  sd1[64]               256   } zeroed together (192 words)
//   66048    : float  sd8[64]               256  /
//   66304    : float  msp1[256]             1024
//   67328    : float  msp8[256]             1024
//   69632    : int    rowlist[K][B]         2097152
//   2166784  : float  Cpart1[16][K][D]      16777216
//   18944000 : float  Cpart8[16][K][D]      16777216
//   total ~35.7 MB (ws_size observed ~539 MB)

extern "C" void kernel_launch(void* const* d_in, const int* in_sizes, int n_in,
                              void* d_out, int out_size, void* d_ws, size_t ws_size,
                              hipStream_t stream) {
  const float* probs = (const float*)d_in[0];
  const float* a1 = (const float*)d_in[1];
  const float* a8 = (const float*)d_in[2];
  const float* m1 = (const float*)d_in[3];
  const float* m8 = (const float*)d_in[4];
  float* out = (float*)d_out;
  char* ws = (char*)d_ws;

  double* entpart = (double*)(ws + 0);
  int* labels = (int*)(ws + 32768);
  int* counts = (int*)(ws + 65536);
  float* sd1 = (float*)(ws + 65792);
  float* sd8 = (float*)(ws + 66048);
  float* msp1 = (float*)(ws + 66304);
  float* msp8 = (float*)(ws + 67328);
  int* rowlist = (int*)(ws + 69632);
  float* Cpart1 = (float*)(ws + 2166784);
  float* Cpart8 = (float*)(ws + 18944000);

  k_init<<<1, 256, 0, stream>>>(counts);
  k_labels<<<B_ / 4, 256, 0, stream>>>(probs, labels, counts, rowlist);
  // single pass over both acts tensors: norm + weighted class-sum fused per wave
  k_classnorm<<<512, 256, 0, stream>>>(a1, a8, counts, rowlist, labels, Cpart1, Cpart8, sd1,
                                       sd8);
  k_entropy<<<ENT_GRID, 256, 0, stream>>>((const f32x4*)m1, (const f32x4*)m8, entpart);
  k_msm<<<512, 256, 0, stream>>>(Cpart1, Cpart8, msp1, msp8);
  k_final<<<1, 256, 0, stream>>>(entpart, counts, sd1, sd8, msp1, msp8, out);
}